// Round 11
// baseline (981.671 us; speedup 1.0000x reference)
//
#include <hip/hip_runtime.h>
#include <hip/hip_bf16.h>

constexpr int B_ = 2, L_ = 2048, D_ = 1024, H_ = 16;

using bf16x8 = __attribute__((ext_vector_type(8))) short;
using f32x4  = __attribute__((ext_vector_type(4))) float;

__device__ __forceinline__ short f2b(float f) {
  union { float f; unsigned int u; } v; v.f = f;
  unsigned int r = (v.u + 0x7FFFu + ((v.u >> 16) & 1u)) >> 16;
  return (short)r;
}
__device__ __forceinline__ float dot4(float4 a, float4 b) {
  return a.x * b.x + a.y * b.y + a.z * b.z + a.w * b.w;
}

// ---------------- fused fp32 GEMM, 128x64 tile, 8x4/thread (2 FLOP per LDS byte) ----------------
// Per-element k-accumulation order unchanged (ascending k) -> bit-identical dq/dk.
__global__ __launch_bounds__(256) void gemm_ff2(const float* __restrict__ A, const float* __restrict__ W1,
                                                const float* __restrict__ W2, float* __restrict__ C1,
                                                float* __restrict__ C2, int N, int K) {
  __shared__ float As[32][132];
  __shared__ float W1s[32][68];
  __shared__ float W2s[32][68];
  int tid = threadIdx.x;
  int tx = tid & 15, ty = tid >> 4;
  int m0 = blockIdx.y * 128, n0 = blockIdx.x * 64;
  float acc1[8][4] = {}, acc2[8][4] = {};
  for (int k0 = 0; k0 < K; k0 += 32) {
#pragma unroll
    for (int i = 0; i < 4; ++i) {
      int idx = i * 256 + tid;
      int m = idx >> 3, k4 = (idx & 7) * 4;
      float4 a = *(const float4*)(A + (size_t)(m0 + m) * K + k0 + k4);
      As[k4 + 0][m] = a.x; As[k4 + 1][m] = a.y; As[k4 + 2][m] = a.z; As[k4 + 3][m] = a.w;
    }
    {
      int wk = tid >> 4, wn = (tid & 15) * 4;
      float4 w1a = *(const float4*)(W1 + (size_t)(k0 + wk) * N + n0 + wn);
      float4 w1b = *(const float4*)(W1 + (size_t)(k0 + 16 + wk) * N + n0 + wn);
      float4 w2a = *(const float4*)(W2 + (size_t)(k0 + wk) * N + n0 + wn);
      float4 w2b = *(const float4*)(W2 + (size_t)(k0 + 16 + wk) * N + n0 + wn);
      *(float4*)&W1s[wk][wn] = w1a;
      *(float4*)&W1s[wk + 16][wn] = w1b;
      *(float4*)&W2s[wk][wn] = w2a;
      *(float4*)&W2s[wk + 16][wn] = w2b;
    }
    __syncthreads();
#pragma unroll
    for (int k = 0; k < 32; ++k) {
      float4 aA = *(float4*)&As[k][ty * 8];
      float4 aB = *(float4*)&As[k][ty * 8 + 4];
      float4 b1 = *(float4*)&W1s[k][tx * 4];
      float4 b2 = *(float4*)&W2s[k][tx * 4];
      float av[8] = {aA.x, aA.y, aA.z, aA.w, aB.x, aB.y, aB.z, aB.w};
      float b1v[4] = {b1.x, b1.y, b1.z, b1.w};
      float b2v[4] = {b2.x, b2.y, b2.z, b2.w};
#pragma unroll
      for (int i = 0; i < 8; ++i)
#pragma unroll
        for (int j = 0; j < 4; ++j) {
          acc1[i][j] += av[i] * b1v[j];
          acc2[i][j] += av[i] * b2v[j];
        }
    }
    __syncthreads();
  }
#pragma unroll
  for (int i = 0; i < 8; ++i) {
    *(float4*)(C1 + (size_t)(m0 + ty * 8 + i) * N + n0 + tx * 4) =
        make_float4(acc1[i][0], acc1[i][1], acc1[i][2], acc1[i][3]);
    *(float4*)(C2 + (size_t)(m0 + ty * 8 + i) * N + n0 + tx * 4) =
        make_float4(acc2[i][0], acc2[i][1], acc2[i][2], acc2[i][3]);
  }
}

// ---------------- transpose+cast: W[K,N] fp32 -> Wt[N,K] bf16 ----------------
__global__ __launch_bounds__(256) void tcast(const float* __restrict__ W, short* __restrict__ Wt,
                                             int N, int K) {
  __shared__ float T[64][65];
  int n0 = blockIdx.x * 64, k0 = blockIdx.y * 64;
  int tid = threadIdx.x;
#pragma unroll
  for (int i = 0; i < 16; ++i) {
    int idx = i * 256 + tid;
    int r = idx >> 6, c = idx & 63;
    T[r][c] = W[(size_t)(k0 + r) * N + n0 + c];
  }
  __syncthreads();
#pragma unroll
  for (int i = 0; i < 16; ++i) {
    int idx = i * 256 + tid;
    int rr = idx >> 6, cc = idx & 63;
    Wt[(size_t)(n0 + rr) * K + k0 + cc] = f2b(T[cc][rr]);
  }
}

// ---------------- MFMA GEMM: C[M,N] = A[M,K] (fp32) @ Wt[N,K]^T (bf16) ----------------
template <int BN>
__global__ __launch_bounds__(256) void gemm_bt(const float* __restrict__ A, const short* __restrict__ Wt,
                                               float* __restrict__ C, int N, int K) {
  constexpr int MT = (BN == 128) ? 4 : 2;
  constexpr int NT = 4;
  __shared__ __align__(16) short As[128 * 32];
  __shared__ __align__(16) short Bs[BN * 32];
  int tid = threadIdx.x;
  int wave = tid >> 6, lane = tid & 63, quad = lane >> 4, l15 = lane & 15;
  int m0 = blockIdx.y * 128, n0 = blockIdx.x * BN;
  int wm = (BN == 128) ? (wave >> 1) * 64 : wave * 32;
  int wn = (BN == 128) ? (wave & 1) * 64 : 0;
  f32x4 acc[MT][NT];
#pragma unroll
  for (int mt = 0; mt < MT; ++mt)
#pragma unroll
    for (int nt = 0; nt < NT; ++nt) acc[mt][nt] = (f32x4){0.f, 0.f, 0.f, 0.f};

  for (int k0 = 0; k0 < K; k0 += 32) {
    __syncthreads();
#pragma unroll
    for (int i = 0; i < 2; ++i) {
      int chunk = i * 256 + tid;
      int m = chunk >> 2, kc = (chunk & 3) * 8;
      const float* ap = A + (size_t)(m0 + m) * K + k0 + kc;
      float4 a0 = *(const float4*)ap;
      float4 a1 = *(const float4*)(ap + 4);
      __hip_bfloat162 c0 = __float22bfloat162_rn(make_float2(a0.x, a0.y));
      __hip_bfloat162 c1 = __float22bfloat162_rn(make_float2(a0.z, a0.w));
      __hip_bfloat162 c2 = __float22bfloat162_rn(make_float2(a1.x, a1.y));
      __hip_bfloat162 c3 = __float22bfloat162_rn(make_float2(a1.z, a1.w));
      uint4 u;
      u.x = *(unsigned int*)&c0; u.y = *(unsigned int*)&c1;
      u.z = *(unsigned int*)&c2; u.w = *(unsigned int*)&c3;
      *(uint4*)&As[m * 32 + kc] = u;
    }
#pragma unroll
    for (int i = 0; i < BN * 4 / 256; ++i) {
      int chunk = i * 256 + tid;
      int n = chunk >> 2, kc = (chunk & 3) * 8;
      uint4 w = *(const uint4*)(Wt + (size_t)(n0 + n) * K + k0 + kc);
      *(uint4*)&Bs[n * 32 + kc] = w;
    }
    __syncthreads();
    bf16x8 af[MT], bf[NT];
#pragma unroll
    for (int mt = 0; mt < MT; ++mt) af[mt] = *(bf16x8*)&As[(wm + mt * 16 + l15) * 32 + quad * 8];
#pragma unroll
    for (int nt = 0; nt < NT; ++nt) bf[nt] = *(bf16x8*)&Bs[(wn + nt * 16 + l15) * 32 + quad * 8];
#pragma unroll
    for (int mt = 0; mt < MT; ++mt)
#pragma unroll
      for (int nt = 0; nt < NT; ++nt)
        acc[mt][nt] = __builtin_amdgcn_mfma_f32_16x16x32_bf16(af[mt], bf[nt], acc[mt][nt], 0, 0, 0);
  }
#pragma unroll
  for (int mt = 0; mt < MT; ++mt)
#pragma unroll
    for (int nt = 0; nt < NT; ++nt)
#pragma unroll
      for (int r = 0; r < 4; ++r)
        C[(size_t)(m0 + wm + mt * 16 + quad * 4 + r) * N + n0 + wn + nt * 16 + l15] = acc[mt][nt][r];
}

// ---------------- MFMA bf16 causal flash attention ----------------
__global__ __launch_bounds__(256) void attn_mfma(const float* __restrict__ qkv, float* __restrict__ outp) {
  __shared__ __align__(16) short Kl[64 * 64];
  __shared__ __align__(16) short Vt[64 * 64];
  __shared__ __align__(16) short Pl[64 * 64];
  int qb = 31 - blockIdx.x, h = blockIdx.y, b = blockIdx.z;
  int tid = threadIdx.x;
  int wave = tid >> 6, lane = tid & 63;
  int quad = lane >> 4, l15 = lane & 15;
  int qrow = qb * 64 + wave * 16 + l15;
  union { bf16x8 v; short u[8]; } qf[2];
  {
    const float* qbase = qkv + (size_t)(b * L_ + qrow) * 3072 + h * 64;
#pragma unroll
    for (int s = 0; s < 2; ++s) {
      float4 a = *(const float4*)(qbase + s * 32 + quad * 8);
      float4 c = *(const float4*)(qbase + s * 32 + quad * 8 + 4);
      qf[s].u[0] = f2b(a.x); qf[s].u[1] = f2b(a.y); qf[s].u[2] = f2b(a.z); qf[s].u[3] = f2b(a.w);
      qf[s].u[4] = f2b(c.x); qf[s].u[5] = f2b(c.y); qf[s].u[6] = f2b(c.z); qf[s].u[7] = f2b(c.w);
    }
  }
  f32x4 Of[4];
  float mrow[4], lrow[4], alpha[4];
#pragma unroll
  for (int dt = 0; dt < 4; ++dt) Of[dt] = (f32x4){0.f, 0.f, 0.f, 0.f};
#pragma unroll
  for (int r = 0; r < 4; ++r) { mrow[r] = -1e30f; lrow[r] = 0.f; }

  for (int kt = 0; kt <= qb; ++kt) {
    __syncthreads();
#pragma unroll
    for (int it = 0; it < 4; ++it) {
      int e4 = tid + it * 256;
      int key = e4 >> 4, d4 = e4 & 15;
      const float* src = qkv + ((size_t)((b * L_ + kt * 64 + key) * 3) + 1) * 1024 + h * 64 + d4 * 4;
      float4 kv = *(const float4*)src;
      short4 kp;
      kp.x = f2b(kv.x); kp.y = f2b(kv.y); kp.z = f2b(kv.z); kp.w = f2b(kv.w);
      int posK = key * 64 + ((((d4 >> 1) ^ (key & 7)) << 3) | ((d4 & 1) << 2));
      *(short4*)&Kl[posK] = kp;
    }
    {
      int key4 = tid >> 4;
      int d4 = tid & 15;
      const float* vsrc = qkv + ((size_t)((b * L_ + kt * 64 + key4 * 4) * 3) + 2) * 1024 + h * 64 + d4 * 4;
      union { float4 v; float a[4]; } v0, v1, v2, v3;
      v0.v = *(const float4*)vsrc;
      v1.v = *(const float4*)(vsrc + 3072);
      v2.v = *(const float4*)(vsrc + 6144);
      v3.v = *(const float4*)(vsrc + 9216);
      int kg = key4 >> 1, k7b = (key4 & 1) * 4;
#pragma unroll
      for (int jj = 0; jj < 4; ++jj) {
        int d = d4 * 4 + jj;
        short4 sv;
        sv.x = f2b(v0.a[jj]); sv.y = f2b(v1.a[jj]); sv.z = f2b(v2.a[jj]); sv.w = f2b(v3.a[jj]);
        *(short4*)&Vt[d * 64 + ((kg ^ (d & 7)) << 3) + k7b] = sv;
      }
    }
    __syncthreads();
    f32x4 sc[4];
#pragma unroll
    for (int nt = 0; nt < 4; ++nt) sc[nt] = (f32x4){0.f, 0.f, 0.f, 0.f};
#pragma unroll
    for (int s = 0; s < 2; ++s) {
#pragma unroll
      for (int nt = 0; nt < 4; ++nt) {
        int key = nt * 16 + l15;
        bf16x8 kf = *(bf16x8*)&Kl[key * 64 + (((4 * s + quad) ^ (key & 7)) << 3)];
        sc[nt] = __builtin_amdgcn_mfma_f32_16x16x32_bf16(qf[s].v, kf, sc[nt], 0, 0, 0);
      }
    }
    bool diag = (kt == qb);
#pragma unroll
    for (int r = 0; r < 4; ++r) {
      float sv[4];
#pragma unroll
      for (int nt = 0; nt < 4; ++nt) {
        float v = sc[nt][r] * 0.125f;
        if (diag && (nt * 16 + l15 > wave * 16 + quad * 4 + r)) v = -1e30f;
        sv[nt] = v;
      }
      float mx = fmaxf(fmaxf(sv[0], sv[1]), fmaxf(sv[2], sv[3]));
      mx = fmaxf(mx, __shfl_xor(mx, 1));
      mx = fmaxf(mx, __shfl_xor(mx, 2));
      mx = fmaxf(mx, __shfl_xor(mx, 4));
      mx = fmaxf(mx, __shfl_xor(mx, 8));
      float mnew = fmaxf(mrow[r], mx);
      float al = __expf(mrow[r] - mnew);
      mrow[r] = mnew;
      alpha[r] = al;
      int prow = wave * 16 + quad * 4 + r;
      int r7 = prow & 7;
      float ps = 0.f;
#pragma unroll
      for (int nt = 0; nt < 4; ++nt) {
        float p = __expf(sv[nt] - mnew);
        ps += p;
        Pl[prow * 64 + ((((nt << 1) + (l15 >> 3)) ^ r7) << 3) + (l15 & 7)] = f2b(p);
      }
      ps += __shfl_xor(ps, 1);
      ps += __shfl_xor(ps, 2);
      ps += __shfl_xor(ps, 4);
      ps += __shfl_xor(ps, 8);
      lrow[r] = lrow[r] * al + ps;
    }
#pragma unroll
    for (int dt = 0; dt < 4; ++dt)
#pragma unroll
      for (int r = 0; r < 4; ++r) Of[dt][r] *= alpha[r];
#pragma unroll
    for (int s = 0; s < 2; ++s) {
      bf16x8 pf = *(bf16x8*)&Pl[(wave * 16 + l15) * 64 + (((4 * s + quad) ^ (l15 & 7)) << 3)];
#pragma unroll
      for (int dt = 0; dt < 4; ++dt) {
        int d = dt * 16 + l15;
        bf16x8 vf = *(bf16x8*)&Vt[d * 64 + (((4 * s + quad) ^ (d & 7)) << 3)];
        Of[dt] = __builtin_amdgcn_mfma_f32_16x16x32_bf16(pf, vf, Of[dt], 0, 0, 0);
      }
    }
  }
#pragma unroll
  for (int r = 0; r < 4; ++r) alpha[r] = 1.f / lrow[r];
  int orow = qb * 64 + wave * 16 + quad * 4;
#pragma unroll
  for (int dt = 0; dt < 4; ++dt)
#pragma unroll
    for (int r = 0; r < 4; ++r)
      outp[(size_t)(b * L_ + orow + r) * 1024 + h * 64 + dt * 16 + l15] = Of[dt][r] * alpha[r];
}

// ---------------- layernorm over last dim D=1024, in place ----------------
__global__ __launch_bounds__(256) void ln_kernel(float* __restrict__ X, const float* __restrict__ g,
                                                 const float* __restrict__ bb) {
  int row = blockIdx.x, tid = threadIdx.x;
  float* xr = X + (size_t)row * D_;
  float v[4], s = 0.f, ss = 0.f;
#pragma unroll
  for (int i = 0; i < 4; ++i) { v[i] = xr[tid + i * 256]; s += v[i]; ss += v[i] * v[i]; }
#pragma unroll
  for (int off = 32; off; off >>= 1) { s += __shfl_xor(s, off); ss += __shfl_xor(ss, off); }
  __shared__ float rs[4], rss[4];
  if ((tid & 63) == 0) { rs[tid >> 6] = s; rss[tid >> 6] = ss; }
  __syncthreads();
  float S = rs[0] + rs[1] + rs[2] + rs[3];
  float SS = rss[0] + rss[1] + rss[2] + rss[3];
  float mean = S * (1.f / 1024.f);
  float var = SS * (1.f / 1024.f) - mean * mean;
  float inv = rsqrtf(var + 1e-5f);
#pragma unroll
  for (int i = 0; i < 4; ++i) {
    int c = tid + i * 256;
    xr[c] = (v[i] - mean) * inv * g[c] + bb[c];
  }
}

// ---------------- fused: LN(ln_g,ln_b) -> LN(dn_g,dn_b) -> gate mix ----------------
__global__ __launch_bounds__(256) void ln2mix_kernel(const float* __restrict__ X,
                                                     const float* __restrict__ g1, const float* __restrict__ b1,
                                                     const float* __restrict__ g2, const float* __restrict__ b2,
                                                     const float* __restrict__ gpre, const float* __restrict__ bgate,
                                                     const float* __restrict__ fo, float* __restrict__ outp) {
  int row = blockIdx.x, tid = threadIdx.x;
  const float* xr = X + (size_t)row * D_;
  __shared__ float rs[4], rss[4];
  float v[4], s = 0.f, ss = 0.f;
#pragma unroll
  for (int i = 0; i < 4; ++i) { v[i] = xr[tid + i * 256]; s += v[i]; ss += v[i] * v[i]; }
#pragma unroll
  for (int off = 32; off; off >>= 1) { s += __shfl_xor(s, off); ss += __shfl_xor(ss, off); }
  if ((tid & 63) == 0) { rs[tid >> 6] = s; rss[tid >> 6] = ss; }
  __syncthreads();
  float S = rs[0] + rs[1] + rs[2] + rs[3];
  float SS = rss[0] + rss[1] + rss[2] + rss[3];
  float mean = S * (1.f / 1024.f);
  float var = SS * (1.f / 1024.f) - mean * mean;
  float inv = rsqrtf(var + 1e-5f);
  s = 0.f; ss = 0.f;
#pragma unroll
  for (int i = 0; i < 4; ++i) {
    int c = tid + i * 256;
    v[i] = (v[i] - mean) * inv * g1[c] + b1[c];
    s += v[i]; ss += v[i] * v[i];
  }
#pragma unroll
  for (int off = 32; off; off >>= 1) { s += __shfl_xor(s, off); ss += __shfl_xor(ss, off); }
  __syncthreads();
  if ((tid & 63) == 0) { rs[tid >> 6] = s; rss[tid >> 6] = ss; }
  __syncthreads();
  S = rs[0] + rs[1] + rs[2] + rs[3];
  SS = rss[0] + rss[1] + rss[2] + rss[3];
  mean = S * (1.f / 1024.f);
  var = SS * (1.f / 1024.f) - mean * mean;
  inv = rsqrtf(var + 1e-5f);
#pragma unroll
  for (int i = 0; i < 4; ++i) {
    int c = tid + i * 256;
    size_t idx = (size_t)row * D_ + c;
    float w = (v[i] - mean) * inv * g2[c] + b2[c];
    float gg = 1.f / (1.f + __expf(-(gpre[idx] + bgate[c])));
    outp[idx] = gg * fo[idx] + (1.f - gg) * w;
  }
}

// ---------------- fused causal depthwise conv (path 0: q) / conv + L2-norm (path 1: k) ----------------
__global__ __launch_bounds__(256) void convnorm_kernel(const float* __restrict__ qin, const float* __restrict__ kin,
                                                       const float* __restrict__ qw, const float* __restrict__ qb,
                                                       const float* __restrict__ kw, const float* __restrict__ kb,
                                                       float* __restrict__ qout, float* __restrict__ kout) {
  int path = blockIdx.y;
  int row = blockIdx.x * 4 + (threadIdx.x >> 6);
  int lane = threadIdx.x & 63;
  int bl = row >> 4, h = row & 15;
  int t = bl & (L_ - 1);
  int d = h * 64 + lane;
  size_t idx = (size_t)bl * D_ + d;
  const float* xin = path ? kin : qin;
  const float* w = path ? kw : qw;
  const float* bias = path ? kb : qb;
  float acc = bias[d];
#pragma unroll
  for (int j = 0; j < 4; ++j) {
    int tt = t - 3 + j;
    if (tt >= 0) acc += w[d * 4 + j] * xin[idx + (size_t)(j - 3) * D_];
  }
  if (path) {
    float n2 = acc * acc;
#pragma unroll
    for (int off = 32; off; off >>= 1) n2 += __shfl_xor(n2, off);
    acc = acc / fmaxf(sqrtf(n2), 1e-12f);
    kout[idx] = acc;
  } else {
    qout[idx] = acc;
  }
}

// ---------------- beta = sigmoid(x @ Wbeta + bbeta) ----------------
__global__ __launch_bounds__(256) void beta_kernel(const float* __restrict__ xf, const float* __restrict__ Wb,
                                                   const float* __restrict__ bb, float* __restrict__ beta) {
  int row = blockIdx.x, tid = threadIdx.x;
  int h = tid & 15, seg = tid >> 4;
  const float* xr = xf + (size_t)row * D_ + seg * 64;
  const float* wp = Wb + (seg * 64) * H_ + h;
  float p = 0.f;
  for (int k = 0; k < 64; ++k) p += xr[k] * wp[k * H_];
  __shared__ float red[16][17];
  red[seg][h] = p;
  __syncthreads();
  if (tid < 16) {
    float s = bb[tid];
#pragma unroll
    for (int s2 = 0; s2 < 16; ++s2) s += red[s2][tid];
    beta[(size_t)row * H_ + tid] = 1.f / (1.f + __expf(-s));
  }
}

// ================= chunked delta scan =================
__global__ __launch_bounds__(256) void prep_kernel(const float* __restrict__ dq, const float* __restrict__ dk,
                                                   const float* __restrict__ beta,
                                                   float* __restrict__ Minv_g, float* __restrict__ Bq_g) {
  __shared__ __align__(16) float Kl[32 * 68];
  __shared__ __align__(16) float Ql[32 * 68];
  __shared__ __align__(16) float Ml[32 * 36];
  __shared__ __align__(16) float Xl[32 * 36];
  __shared__ __align__(16) float bl[32];
  int c = blockIdx.x, bh = blockIdx.y;
  int b = bh >> 4, h = bh & 15;
  int t0 = c * 32;
  int tid = threadIdx.x;
#pragma unroll
  for (int rep = 0; rep < 2; ++rep) {
    int id = tid * 2 + rep;
    int r = id >> 4, j4 = id & 15;
    size_t gi = (size_t)(b * L_ + t0 + r) * 1024 + h * 64 + j4 * 4;
    *(float4*)&Kl[r * 68 + j4 * 4] = *(const float4*)&dk[gi];
    *(float4*)&Ql[r * 68 + j4 * 4] = *(const float4*)&dq[gi];
  }
  if (tid < 32) bl[tid] = beta[(size_t)(b * L_ + t0 + tid) * 16 + h];
  __syncthreads();
  int t = tid >> 3, s0 = (tid & 7) * 4;
  float accA[4] = {0.f, 0.f, 0.f, 0.f}, accB[4] = {0.f, 0.f, 0.f, 0.f};
#pragma unroll
  for (int k4 = 0; k4 < 16; ++k4) {
    float4 kt = *(float4*)&Kl[t * 68 + k4 * 4];
    float4 qt = *(float4*)&Ql[t * 68 + k4 * 4];
#pragma unroll
    for (int j = 0; j < 4; ++j) {
      float4 ks = *(float4*)&Kl[(s0 + j) * 68 + k4 * 4];
      accA[j] += dot4(kt, ks);
      accB[j] += dot4(qt, ks);
    }
  }
  float4 bq;
  float* bqp = (float*)&bq;
#pragma unroll
  for (int j = 0; j < 4; ++j) {
    int s = s0 + j;
    Ml[t * 36 + s] = (s < t) ? bl[t] * accA[j] : ((s == t) ? 1.f : 0.f);
    bqp[j] = (s < t) ? accB[j] : 0.f;
  }
  size_t obase = ((size_t)(bh * 64 + c) * 32 + t) * 32 + s0;
  *(float4*)&Bq_g[obase] = bq;
  __syncthreads();
  if (tid < 32) {
    int col = tid;
    float xr[32];
#pragma unroll
    for (int tt = 0; tt < 32; ++tt) {
      float x = (tt == col) ? 1.f : 0.f;
#pragma unroll
      for (int s = 0; s < tt; ++s) x -= Ml[tt * 36 + s] * xr[s];
      xr[tt] = x;
      Xl[tt * 36 + col] = x;
    }
  }
  __syncthreads();
  float4 mv = make_float4(Xl[t * 36 + s0], Xl[t * 36 + s0 + 1], Xl[t * 36 + s0 + 2], Xl[t * 36 + s0 + 3]);
  *(float4*)&Minv_g[obase] = mv;
}

// double-buffered; XCD-locality swizzle (bh = blockIdx & 31).
__global__ __launch_bounds__(256) void delta_kernel(const float* __restrict__ dq, const float* __restrict__ dk,
                                                    const float* __restrict__ dv, const float* __restrict__ beta,
                                                    const float* __restrict__ Minv_g, const float* __restrict__ Bq_g,
                                                    float* __restrict__ ys, float* __restrict__ outS,
                                                    float* __restrict__ outZ) {
  __shared__ __align__(16) float Kl[2][32 * 68];
  __shared__ __align__(16) float Ql[2][32 * 68];
  __shared__ __align__(16) float Vl[2][32 * 9];
  __shared__ __align__(16) float Mil[2][32 * 36];
  __shared__ __align__(16) float Bql[2][32 * 36];
  __shared__ __align__(16) float bl[2][32];
  __shared__ __align__(16) float S0l[8 * 68];
  __shared__ __align__(16) float Y0l[32 * 9];
  __shared__ __align__(16) float RtmpTl[8 * 36];
  __shared__ __align__(16) float RTl[8 * 36];
  __shared__ __align__(16) float z0l[68];
  __shared__ __align__(16) float qzl[32];
  __shared__ __align__(16) float denl[32];
  int bh = blockIdx.x & 31, grp = blockIdx.x >> 5;
  int b = bh >> 4, h = bh & 15;
  int i0 = grp * 8;
  int tid = threadIdx.x;
  int r = tid >> 3, j8 = (tid & 7) * 8, s4 = tid & 7;
  size_t kqbase = (size_t)(b * L_) * 1024 + h * 64;

  for (int e = tid; e < 8 * 68; e += 256) S0l[e] = 0.f;
  if (tid < 68) z0l[tid] = 0.f;

  float4 kA, kB, qA, qB, mr, br;
  float vr, blr = 0.f;
  {
    const float* kp = dk + kqbase + (size_t)r * 1024 + j8;
    kA = ((const float4*)kp)[0]; kB = ((const float4*)kp)[1];
    const float* qp = dq + kqbase + (size_t)r * 1024 + j8;
    qA = ((const float4*)qp)[0]; qB = ((const float4*)qp)[1];
    size_t gb = ((size_t)(bh * 64) * 32 + r) * 32 + s4 * 4;
    mr = *(const float4*)&Minv_g[gb];
    br = *(const float4*)&Bq_g[gb];
    vr = dv[(size_t)(b * L_ + r) * 1024 + h * 64 + i0 + s4];
    if (tid < 32) blr = beta[(size_t)(b * L_ + tid) * 16 + h];
  }
  *(float4*)&Kl[0][r * 68 + j8] = kA; *(float4*)&Kl[0][r * 68 + j8 + 4] = kB;
  *(float4*)&Ql[0][r * 68 + j8] = qA; *(float4*)&Ql[0][r * 68 + j8 + 4] = qB;
  *(float4*)&Mil[0][r * 36 + s4 * 4] = mr;
  *(float4*)&Bql[0][r * 36 + s4 * 4] = br;
  Vl[0][r * 9 + s4] = vr;
  if (tid < 32) bl[0][tid] = blr;
  __syncthreads();

  for (int c = 0; c < 64; ++c) {
    int cur = c & 1, nxt = cur ^ 1;
    int cn = (c + 1 < 64) ? c + 1 : 63;
    int t0n = cn * 32;
    {
      const float* kp = dk + kqbase + (size_t)(t0n + r) * 1024 + j8;
      kA = ((const float4*)kp)[0]; kB = ((const float4*)kp)[1];
      const float* qp = dq + kqbase + (size_t)(t0n + r) * 1024 + j8;
      qA = ((const float4*)qp)[0]; qB = ((const float4*)qp)[1];
      size_t gb = ((size_t)(bh * 64 + cn) * 32 + r) * 32 + s4 * 4;
      mr = *(const float4*)&Minv_g[gb];
      br = *(const float4*)&Bq_g[gb];
      vr = dv[(size_t)(b * L_ + t0n + r) * 1024 + h * 64 + i0 + s4];
      if (tid < 32) blr = beta[(size_t)(b * L_ + t0n + tid) * 16 + h];
    }
    int t0 = c * 32;
    // ---- P1 ----
    {
      int rr = tid >> 3;
      int iq = (tid >> 1) & 3;
      int jh = tid & 1;
      float aK0 = 0.f, aK1 = 0.f, aY0 = 0.f, aY1 = 0.f;
#pragma unroll
      for (int jj = 0; jj < 8; ++jj) {
        int j4 = jh * 8 + jj;
        float4 k = *(float4*)&Kl[cur][rr * 68 + j4 * 4];
        float4 q = *(float4*)&Ql[cur][rr * 68 + j4 * 4];
        float4 sA = *(float4*)&S0l[iq * 68 + j4 * 4];
        float4 sB = *(float4*)&S0l[(iq + 4) * 68 + j4 * 4];
        aK0 += dot4(k, sA); aK1 += dot4(k, sB);
        aY0 += dot4(q, sA); aY1 += dot4(q, sB);
      }
      aK0 += __shfl_xor(aK0, 1); aK1 += __shfl_xor(aK1, 1);
      aY0 += __shfl_xor(aY0, 1); aY1 += __shfl_xor(aY1, 1);
      if (jh == 0) {
        float be = bl[cur][rr];
        RtmpTl[iq * 36 + rr] = be * (Vl[cur][rr * 9 + iq] - aK0);
        RtmpTl[(iq + 4) * 36 + rr] = be * (Vl[cur][rr * 9 + iq + 4] - aK1);
        Y0l[rr * 9 + iq] = aY0;
        Y0l[rr * 9 + iq + 4] = aY1;
      }
      if (tid < 32) {
        float a = 0.f;
#pragma unroll
        for (int j4 = 0; j4 < 16; ++j4) {
          float4 q = *(float4*)&Ql[cur][tid * 68 + j4 * 4];
          float4 z = *(float4*)&z0l[j4 * 4];
          a += dot4(q, z);
        }
        qzl[tid] = a;
      }
    }
    __syncthreads();
    // ---- P2 ----
    {
      int t = tid >> 3, i = tid & 7;
      float acc = 0.f;
#pragma unroll
      for (int s4i = 0; s4i < 8; ++s4i) {
        float4 m = *(float4*)&Mil[cur][t * 36 + s4i * 4];
        float4 rt = *(float4*)&RtmpTl[i * 36 + s4i * 4];
        acc += dot4(m, rt);
      }
      RTl[i * 36 + t] = acc;
      if (tid < 32) {
        float a = qzl[tid];
#pragma unroll
        for (int s4i = 0; s4i < 8; ++s4i) {
          float4 bq = *(float4*)&Bql[cur][tid * 36 + s4i * 4];
          float4 be = *(float4*)&bl[cur][s4i * 4];
          a += dot4(bq, be);
        }
        denl[tid] = a + 1e-6f;
      }
    }
    __syncthreads();
    // ---- P3a ----
    {
      int t = tid >> 3, i = tid & 7;
      float acc = 0.f;
#pragma unroll
      for (int s4i = 0; s4i < 8; ++s4i) {
        float4 bq = *(float4*)&Bql[cur][t * 36 + s4i * 4];
        float4 rt = *(float4*)&RTl[i * 36 + s4i * 4];
        acc += dot4(bq, rt);
      }
      float y = (Y0l[t * 9 + i] + acc) / denl[t];
      ys[(size_t)(b * L_ + t0 + t) * 1024 + h * 64 + i0 + i] = y;
    }
    // ---- P3b ----
    {
      int i = tid >> 5;
      int j2 = (tid & 31) * 2;
      float a0 = S0l[i * 68 + j2];
      float a1 = S0l[i * 68 + j2 + 1];
#pragma unroll
      for (int s4i = 0; s4i < 8; ++s4i) {
        float4 rt = *(float4*)&RTl[i * 36 + s4i * 4];
        float2 k0 = *(float2*)&Kl[cur][(s4i * 4 + 0) * 68 + j2];
        float2 k1 = *(float2*)&Kl[cur][(s4i * 4 + 1) * 68 + j2];
        float2 k2 = *(float2*)&Kl[cur][(s4i * 4 + 2) * 68 + j2];
        float2 k3 = *(float2*)&Kl[cur][(s4i * 4 + 3) * 68 + j2];
        a0 += rt.x * k0.x + rt.y * k1.x + rt.z * k2.x + rt.w * k3.x;
        a1 += rt.x * k0.y + rt.y * k1.y + rt.z * k2.y + rt.w * k3.y;
      }
      S0l[i * 68 + j2] = a0;
      S0l[i * 68 + j2 + 1] = a1;
    }
    if (tid < 64) {
      float a = z0l[tid];
#pragma unroll
      for (int s = 0; s < 32; ++s) a += bl[cur][s] * Kl[cur][s * 68 + tid];
      z0l[tid] = a;
    }
    *(float4*)&Kl[nxt][r * 68 + j8] = kA; *(float4*)&Kl[nxt][r * 68 + j8 + 4] = kB;
    *(float4*)&Ql[nxt][r * 68 + j8] = qA; *(float4*)&Ql[nxt][r * 68 + j8 + 4] = qB;
    *(float4*)&Mil[nxt][r * 36 + s4 * 4] = mr;
    *(float4*)&Bql[nxt][r * 36 + s4 * 4] = br;
    Vl[nxt][r * 9 + s4] = vr;
    if (tid < 32) bl[nxt][tid] = blr;
    __syncthreads();
  }
  {
    int i = tid >> 5, j2 = (tid & 31) * 2;
    *(float2*)&outS[((size_t)(bh * 64) + i0 + i) * 64 + j2] = *(float2*)&S0l[i * 68 + j2];
  }
  if (grp == 0 && tid < 64) outZ[bh * 64 + tid] = z0l[tid];
}

extern "C" void kernel_launch(void* const* d_in, const int* in_sizes, int n_in,
                              void* d_out, int out_size, void* d_ws, size_t ws_size,
                              hipStream_t stream) {
  const float* x     = (const float*)d_in[0];
  const float* Wqkv  = (const float*)d_in[1];
  const float* Wout  = (const float*)d_in[2];
  const float* Wgate = (const float*)d_in[3];
  const float* bgate = (const float*)d_in[4];
  const float* fn_g  = (const float*)d_in[5];
  const float* fn_b  = (const float*)d_in[6];
  const float* dn_g  = (const float*)d_in[7];
  const float* dn_b  = (const float*)d_in[8];
  const float* dWq   = (const float*)d_in[9];
  const float* dWk   = (const float*)d_in[10];
  const float* dWv   = (const float*)d_in[11];
  const float* dWo   = (const float*)d_in[12];
  const float* Wbeta = (const float*)d_in[13];
  const float* bbeta = (const float*)d_in[14];
  const float* cq_w  = (const float*)d_in[15];
  const float* cq_b  = (const float*)d_in[16];
  const float* ck_w  = (const float*)d_in[17];
  const float* ck_b  = (const float*)d_in[18];
  const float* ln_g  = (const float*)d_in[19];
  const float* ln_b  = (const float*)d_in[20];

  float* ws = (float*)d_ws;
  float* qkv    = ws;              // [0,12M)
  float* dv     = ws;              // [0,4M)
  float* dqc    = ws + 4194304;    // [4M,8M)
  float* dkc    = ws + 8388608;    // [8M,12M)
  float* attnO  = ws + 12582912;   // [12M,16M)
  float* Minv_g = ws + 12582912;   // [12M,14M)
  float* Bq_g   = ws + 14680064;   // [14M,16M)
  float* do1    = ws + 12582912;
  float* fo     = ws + 16777216;   // [16M,20M)
  float* dqp    = ws + 20971520;   // [20M,24M)
  float* gpre   = ws + 20971520;
  float* dkp    = ws + 25165824;   // [24M,28M)
  float* ysb    = ws + 25165824;
  float* betab  = ws + 29360128;   // [28M,+64K floats)

  short* Wqkvt = (short*)(ws + 12582912);
  short* Woutt = (short*)(ws + 20971520);
  short* Wvt   = (short*)(ws + 8388608);
  short* wtg   = (short*)(ws + 12582912);
  short* Wot   = (short*)(ws + 4194304);

  float* out  = (float*)d_out;
  float* outS = out + 4194304;
  float* outZ = out + 4325376;

  // ---- flash branch ----
  tcast<<<dim3(48, 16), 256, 0, stream>>>(Wqkv, Wqkvt, 3072, 1024);
  gemm_bt<128><<<dim3(24, 32), 256, 0, stream>>>(x, Wqkvt, qkv, 3072, 1024);
  attn_mfma<<<dim3(32, H_, B_), 256, 0, stream>>>(qkv, attnO);
  tcast<<<dim3(16, 16), 256, 0, stream>>>(Wout, Woutt, 1024, 1024);
  gemm_bt<64><<<dim3(16, 32), 256, 0, stream>>>(attnO, Woutt, fo, 1024, 1024);
  ln_kernel<<<4096, 256, 0, stream>>>(fo, fn_g, fn_b);
  // ---- delta branch ----
  gemm_ff2<<<dim3(16, 32), 256, 0, stream>>>(x, dWq, dWk, dqp, dkp, 1024, 1024); // kills Woutt
  tcast<<<dim3(16, 16), 256, 0, stream>>>(dWv, Wvt, 1024, 1024);                 // qkv dead
  gemm_bt<64><<<dim3(16, 32), 256, 0, stream>>>(x, Wvt, dv, 1024, 1024);
  convnorm_kernel<<<dim3(16384, 2), 256, 0, stream>>>(dqp, dkp, cq_w, cq_b, ck_w, ck_b, dqc, dkc); // kills Wvt
  beta_kernel<<<4096, 256, 0, stream>>>(x, Wbeta, bbeta, betab);
  tcast<<<dim3(16, 16), 256, 0, stream>>>(Wgate, wtg, 1024, 1024);               // attnO dead
  gemm_bt<64><<<dim3(16, 32), 256, 0, stream>>>(x, wtg, gpre, 1024, 1024);       // kills dqp
  prep_kernel<<<dim3(64, 32), 256, 0, stream>>>(dqc, dkc, betab, Minv_g, Bq_g);  // kills wtg
  delta_kernel<<<256, 256, 0, stream>>>(dqc, dkc, dv, betab, Minv_g, Bq_g, ysb, outS, outZ);
  tcast<<<dim3(16, 16), 256, 0, stream>>>(dWo, Wot, 1024, 1024);                 // dqc dead
  gemm_bt<64><<<dim3(16, 32), 256, 0, stream>>>(ysb, Wot, do1, 1024, 1024);      // kills Minv/Bq
  ln2mix_kernel<<<4096, 256, 0, stream>>>(do1, ln_g, ln_b, dn_g, dn_b, gpre, bgate, fo, out);
}

// Round 12
// 920.150 us; speedup vs baseline: 1.0669x; 1.0669x over previous
//
#include <hip/hip_runtime.h>
#include <hip/hip_bf16.h>

constexpr int B_ = 2, L_ = 2048, D_ = 1024, H_ = 16;

using bf16x8 = __attribute__((ext_vector_type(8))) short;
using f32x4  = __attribute__((ext_vector_type(4))) float;

__device__ __forceinline__ short f2b(float f) {
  union { float f; unsigned int u; } v; v.f = f;
  unsigned int r = (v.u + 0x7FFFu + ((v.u >> 16) & 1u)) >> 16;
  return (short)r;
}
__device__ __forceinline__ float dot4(float4 a, float4 b) {
  return a.x * b.x + a.y * b.y + a.z * b.z + a.w * b.w;
}

// ---------------- fused fp32 GEMM (round-8 shape): C1 = A@W1, C2 = A@W2 ----------------
__global__ __launch_bounds__(256) void gemm_ff2(const float* __restrict__ A, const float* __restrict__ W1,
                                                const float* __restrict__ W2, float* __restrict__ C1,
                                                float* __restrict__ C2, int N, int K) {
  __shared__ float As[16][68];
  __shared__ float W1s[16][68];
  __shared__ float W2s[16][68];
  int tid = threadIdx.x;
  int tx = tid & 15, ty = tid >> 4;
  int m0 = blockIdx.y * 64, n0 = blockIdx.x * 64;
  int am = tid >> 2, ak = (tid & 3) * 4;
  int wk = tid >> 4, wn = (tid & 15) * 4;
  float acc1[4][4] = {}, acc2[4][4] = {};
  for (int k0 = 0; k0 < K; k0 += 16) {
    float4 a = *(const float4*)(A + (size_t)(m0 + am) * K + k0 + ak);
    float4 w1 = *(const float4*)(W1 + (size_t)(k0 + wk) * N + n0 + wn);
    float4 w2 = *(const float4*)(W2 + (size_t)(k0 + wk) * N + n0 + wn);
    As[ak + 0][am] = a.x; As[ak + 1][am] = a.y; As[ak + 2][am] = a.z; As[ak + 3][am] = a.w;
    *(float4*)&W1s[wk][wn] = w1;
    *(float4*)&W2s[wk][wn] = w2;
    __syncthreads();
#pragma unroll
    for (int k = 0; k < 16; ++k) {
      float4 a4 = *(float4*)&As[k][ty * 4];
      float4 b1 = *(float4*)&W1s[k][tx * 4];
      float4 b2 = *(float4*)&W2s[k][tx * 4];
      float av[4] = {a4.x, a4.y, a4.z, a4.w};
      float b1v[4] = {b1.x, b1.y, b1.z, b1.w};
      float b2v[4] = {b2.x, b2.y, b2.z, b2.w};
#pragma unroll
      for (int i = 0; i < 4; ++i)
#pragma unroll
        for (int j = 0; j < 4; ++j) {
          acc1[i][j] += av[i] * b1v[j];
          acc2[i][j] += av[i] * b2v[j];
        }
    }
    __syncthreads();
  }
#pragma unroll
  for (int i = 0; i < 4; ++i) {
    *(float4*)(C1 + (size_t)(m0 + ty * 4 + i) * N + n0 + tx * 4) =
        make_float4(acc1[i][0], acc1[i][1], acc1[i][2], acc1[i][3]);
    *(float4*)(C2 + (size_t)(m0 + ty * 4 + i) * N + n0 + tx * 4) =
        make_float4(acc2[i][0], acc2[i][1], acc2[i][2], acc2[i][3]);
  }
}

// ---------------- transpose+cast: W[K,N] fp32 -> Wt[N,K] bf16 ----------------
__global__ __launch_bounds__(256) void tcast(const float* __restrict__ W, short* __restrict__ Wt,
                                             int N, int K) {
  __shared__ float T[64][65];
  int n0 = blockIdx.x * 64, k0 = blockIdx.y * 64;
  int tid = threadIdx.x;
#pragma unroll
  for (int i = 0; i < 16; ++i) {
    int idx = i * 256 + tid;
    int r = idx >> 6, c = idx & 63;
    T[r][c] = W[(size_t)(k0 + r) * N + n0 + c];
  }
  __syncthreads();
#pragma unroll
  for (int i = 0; i < 16; ++i) {
    int idx = i * 256 + tid;
    int rr = idx >> 6, cc = idx & 63;
    Wt[(size_t)(n0 + rr) * K + k0 + cc] = f2b(T[cc][rr]);
  }
}

// two-weight tcast (1024x1024 each), blockIdx.z selects
__global__ __launch_bounds__(256) void tcast2(const float* __restrict__ W1, const float* __restrict__ W2,
                                              short* __restrict__ Wt1, short* __restrict__ Wt2) {
  __shared__ float T[64][65];
  const float* W = blockIdx.z ? W2 : W1;
  short* Wt = blockIdx.z ? Wt2 : Wt1;
  int n0 = blockIdx.x * 64, k0 = blockIdx.y * 64;
  int tid = threadIdx.x;
#pragma unroll
  for (int i = 0; i < 16; ++i) {
    int idx = i * 256 + tid;
    int r = idx >> 6, c = idx & 63;
    T[r][c] = W[(size_t)(k0 + r) * 1024 + n0 + c];
  }
  __syncthreads();
#pragma unroll
  for (int i = 0; i < 16; ++i) {
    int idx = i * 256 + tid;
    int rr = idx >> 6, cc = idx & 63;
    Wt[(size_t)(n0 + rr) * 1024 + k0 + cc] = f2b(T[cc][rr]);
  }
}

// ---------------- MFMA GEMM core (shared) ----------------
template <int BN, typename CT>
__device__ __forceinline__ void gemm_bt_body(const float* __restrict__ A, const short* __restrict__ Wt,
                                             CT* __restrict__ C, int N, int K, int bx, int by) {
  constexpr int MT = (BN == 128) ? 4 : 2;
  constexpr int NT = 4;
  __shared__ __align__(16) short As[128 * 32];
  __shared__ __align__(16) short Bs[BN * 32];
  int tid = threadIdx.x;
  int wave = tid >> 6, lane = tid & 63, quad = lane >> 4, l15 = lane & 15;
  int m0 = by * 128, n0 = bx * BN;
  int wm = (BN == 128) ? (wave >> 1) * 64 : wave * 32;
  int wn = (BN == 128) ? (wave & 1) * 64 : 0;
  f32x4 acc[MT][NT];
#pragma unroll
  for (int mt = 0; mt < MT; ++mt)
#pragma unroll
    for (int nt = 0; nt < NT; ++nt) acc[mt][nt] = (f32x4){0.f, 0.f, 0.f, 0.f};

  for (int k0 = 0; k0 < K; k0 += 32) {
    __syncthreads();
#pragma unroll
    for (int i = 0; i < 2; ++i) {
      int chunk = i * 256 + tid;
      int m = chunk >> 2, kc = (chunk & 3) * 8;
      const float* ap = A + (size_t)(m0 + m) * K + k0 + kc;
      float4 a0 = *(const float4*)ap;
      float4 a1 = *(const float4*)(ap + 4);
      __hip_bfloat162 c0 = __float22bfloat162_rn(make_float2(a0.x, a0.y));
      __hip_bfloat162 c1 = __float22bfloat162_rn(make_float2(a0.z, a0.w));
      __hip_bfloat162 c2 = __float22bfloat162_rn(make_float2(a1.x, a1.y));
      __hip_bfloat162 c3 = __float22bfloat162_rn(make_float2(a1.z, a1.w));
      uint4 u;
      u.x = *(unsigned int*)&c0; u.y = *(unsigned int*)&c1;
      u.z = *(unsigned int*)&c2; u.w = *(unsigned int*)&c3;
      *(uint4*)&As[m * 32 + kc] = u;
    }
#pragma unroll
    for (int i = 0; i < BN * 4 / 256; ++i) {
      int chunk = i * 256 + tid;
      int n = chunk >> 2, kc = (chunk & 3) * 8;
      uint4 w = *(const uint4*)(Wt + (size_t)(n0 + n) * K + k0 + kc);
      *(uint4*)&Bs[n * 32 + kc] = w;
    }
    __syncthreads();
    bf16x8 af[MT], bf[NT];
#pragma unroll
    for (int mt = 0; mt < MT; ++mt) af[mt] = *(bf16x8*)&As[(wm + mt * 16 + l15) * 32 + quad * 8];
#pragma unroll
    for (int nt = 0; nt < NT; ++nt) bf[nt] = *(bf16x8*)&Bs[(wn + nt * 16 + l15) * 32 + quad * 8];
#pragma unroll
    for (int mt = 0; mt < MT; ++mt)
#pragma unroll
      for (int nt = 0; nt < NT; ++nt)
        acc[mt][nt] = __builtin_amdgcn_mfma_f32_16x16x32_bf16(af[mt], bf[nt], acc[mt][nt], 0, 0, 0);
  }
#pragma unroll
  for (int mt = 0; mt < MT; ++mt)
#pragma unroll
    for (int nt = 0; nt < NT; ++nt)
#pragma unroll
      for (int r = 0; r < 4; ++r) {
        size_t idx = (size_t)(m0 + wm + mt * 16 + quad * 4 + r) * N + n0 + wn + nt * 16 + l15;
        if constexpr (sizeof(CT) == 2) C[idx] = f2b(acc[mt][nt][r]);
        else C[idx] = acc[mt][nt][r];
      }
}

template <int BN>
__global__ __launch_bounds__(256) void gemm_bt(const float* __restrict__ A, const short* __restrict__ Wt,
                                               float* __restrict__ C, int N, int K) {
  gemm_bt_body<BN, float>(A, Wt, C, N, K, blockIdx.x, blockIdx.y);
}

// bf16-output variant (for qkv)
__global__ __launch_bounds__(256) void gemm_bt_h(const float* __restrict__ A, const short* __restrict__ Wt,
                                                 short* __restrict__ C, int N, int K) {
  gemm_bt_body<128, short>(A, Wt, C, N, K, blockIdx.x, blockIdx.y);
}

// two-GEMM variant: z selects (Wt1->C1) vs (Wt2->C2), 1024x1024
__global__ __launch_bounds__(256) void gemm_bt2(const float* __restrict__ A, const short* __restrict__ Wt1,
                                                const short* __restrict__ Wt2, float* __restrict__ C1,
                                                float* __restrict__ C2) {
  gemm_bt_body<64, float>(A, blockIdx.z ? Wt2 : Wt1, blockIdx.z ? C2 : C1, 1024, 1024,
                          blockIdx.x, blockIdx.y);
}

// ---------------- MFMA bf16 causal flash attention (bf16 qkv input) ----------------
__global__ __launch_bounds__(256) void attn_mfma(const short* __restrict__ qkv, float* __restrict__ outp) {
  __shared__ __align__(16) short Kl[64 * 64];
  __shared__ __align__(16) short Vt[64 * 64];
  __shared__ __align__(16) short Pl[64 * 64];
  int qb = 31 - blockIdx.x, h = blockIdx.y, b = blockIdx.z;
  int tid = threadIdx.x;
  int wave = tid >> 6, lane = tid & 63;
  int quad = lane >> 4, l15 = lane & 15;
  int qrow = qb * 64 + wave * 16 + l15;
  bf16x8 qf[2];
  {
    const short* qbase = qkv + (size_t)(b * L_ + qrow) * 3072 + h * 64;
#pragma unroll
    for (int s = 0; s < 2; ++s) qf[s] = *(const bf16x8*)(qbase + s * 32 + quad * 8);
  }
  f32x4 Of[4];
  float mrow[4], lrow[4], alpha[4];
#pragma unroll
  for (int dt = 0; dt < 4; ++dt) Of[dt] = (f32x4){0.f, 0.f, 0.f, 0.f};
#pragma unroll
  for (int r = 0; r < 4; ++r) { mrow[r] = -1e30f; lrow[r] = 0.f; }

  for (int kt = 0; kt <= qb; ++kt) {
    __syncthreads();
    // ---- K staging: 512 chunks of 8 bf16, swizzled ----
#pragma unroll
    for (int it = 0; it < 2; ++it) {
      int e8 = tid + it * 256;
      int key = e8 >> 3, g = e8 & 7;
      const short* src = qkv + ((size_t)((b * L_ + kt * 64 + key) * 3) + 1) * 1024 + h * 64 + g * 8;
      *(bf16x8*)&Kl[key * 64 + ((g ^ (key & 7)) << 3)] = *(const bf16x8*)src;
    }
    // ---- V staging: 4key x 4d register micro-transpose (bf16 loads) ----
    {
      int key4 = tid >> 4;
      int d4 = tid & 15;
      const short* vsrc = qkv + ((size_t)((b * L_ + kt * 64 + key4 * 4) * 3) + 2) * 1024 + h * 64 + d4 * 4;
      short4 v0 = *(const short4*)vsrc;
      short4 v1 = *(const short4*)(vsrc + 3072);
      short4 v2 = *(const short4*)(vsrc + 6144);
      short4 v3 = *(const short4*)(vsrc + 9216);
      short vr0[4] = {v0.x, v0.y, v0.z, v0.w};
      short vr1[4] = {v1.x, v1.y, v1.z, v1.w};
      short vr2[4] = {v2.x, v2.y, v2.z, v2.w};
      short vr3[4] = {v3.x, v3.y, v3.z, v3.w};
      int kg = key4 >> 1, k7b = (key4 & 1) * 4;
#pragma unroll
      for (int jj = 0; jj < 4; ++jj) {
        int d = d4 * 4 + jj;
        short4 sv;
        sv.x = vr0[jj]; sv.y = vr1[jj]; sv.z = vr2[jj]; sv.w = vr3[jj];
        *(short4*)&Vt[d * 64 + ((kg ^ (d & 7)) << 3) + k7b] = sv;
      }
    }
    __syncthreads();
    f32x4 sc[4];
#pragma unroll
    for (int nt = 0; nt < 4; ++nt) sc[nt] = (f32x4){0.f, 0.f, 0.f, 0.f};
#pragma unroll
    for (int s = 0; s < 2; ++s) {
#pragma unroll
      for (int nt = 0; nt < 4; ++nt) {
        int key = nt * 16 + l15;
        bf16x8 kf = *(bf16x8*)&Kl[key * 64 + (((4 * s + quad) ^ (key & 7)) << 3)];
        sc[nt] = __builtin_amdgcn_mfma_f32_16x16x32_bf16(qf[s], kf, sc[nt], 0, 0, 0);
      }
    }
    bool diag = (kt == qb);
#pragma unroll
    for (int r = 0; r < 4; ++r) {
      float sv[4];
#pragma unroll
      for (int nt = 0; nt < 4; ++nt) {
        float v = sc[nt][r] * 0.125f;
        if (diag && (nt * 16 + l15 > wave * 16 + quad * 4 + r)) v = -1e30f;
        sv[nt] = v;
      }
      float mx = fmaxf(fmaxf(sv[0], sv[1]), fmaxf(sv[2], sv[3]));
      mx = fmaxf(mx, __shfl_xor(mx, 1));
      mx = fmaxf(mx, __shfl_xor(mx, 2));
      mx = fmaxf(mx, __shfl_xor(mx, 4));
      mx = fmaxf(mx, __shfl_xor(mx, 8));
      float mnew = fmaxf(mrow[r], mx);
      float al = __expf(mrow[r] - mnew);
      mrow[r] = mnew;
      alpha[r] = al;
      int prow = wave * 16 + quad * 4 + r;
      int r7 = prow & 7;
      float ps = 0.f;
#pragma unroll
      for (int nt = 0; nt < 4; ++nt) {
        float p = __expf(sv[nt] - mnew);
        ps += p;
        Pl[prow * 64 + ((((nt << 1) + (l15 >> 3)) ^ r7) << 3) + (l15 & 7)] = f2b(p);
      }
      ps += __shfl_xor(ps, 1);
      ps += __shfl_xor(ps, 2);
      ps += __shfl_xor(ps, 4);
      ps += __shfl_xor(ps, 8);
      lrow[r] = lrow[r] * al + ps;
    }
#pragma unroll
    for (int dt = 0; dt < 4; ++dt)
#pragma unroll
      for (int r = 0; r < 4; ++r) Of[dt][r] *= alpha[r];
#pragma unroll
    for (int s = 0; s < 2; ++s) {
      bf16x8 pf = *(bf16x8*)&Pl[(wave * 16 + l15) * 64 + (((4 * s + quad) ^ (l15 & 7)) << 3)];
#pragma unroll
      for (int dt = 0; dt < 4; ++dt) {
        int d = dt * 16 + l15;
        bf16x8 vf = *(bf16x8*)&Vt[d * 64 + (((4 * s + quad) ^ (d & 7)) << 3)];
        Of[dt] = __builtin_amdgcn_mfma_f32_16x16x32_bf16(pf, vf, Of[dt], 0, 0, 0);
      }
    }
  }
#pragma unroll
  for (int r = 0; r < 4; ++r) alpha[r] = 1.f / lrow[r];
  int orow = qb * 64 + wave * 16 + quad * 4;
#pragma unroll
  for (int dt = 0; dt < 4; ++dt)
#pragma unroll
    for (int r = 0; r < 4; ++r)
      outp[(size_t)(b * L_ + orow + r) * 1024 + h * 64 + dt * 16 + l15] = Of[dt][r] * alpha[r];
}

// ---------------- layernorm over last dim D=1024, in place ----------------
__global__ __launch_bounds__(256) void ln_kernel(float* __restrict__ X, const float* __restrict__ g,
                                                 const float* __restrict__ bb) {
  int row = blockIdx.x, tid = threadIdx.x;
  float* xr = X + (size_t)row * D_;
  float v[4], s = 0.f, ss = 0.f;
#pragma unroll
  for (int i = 0; i < 4; ++i) { v[i] = xr[tid + i * 256]; s += v[i]; ss += v[i] * v[i]; }
#pragma unroll
  for (int off = 32; off; off >>= 1) { s += __shfl_xor(s, off); ss += __shfl_xor(ss, off); }
  __shared__ float rs[4], rss[4];
  if ((tid & 63) == 0) { rs[tid >> 6] = s; rss[tid >> 6] = ss; }
  __syncthreads();
  float S = rs[0] + rs[1] + rs[2] + rs[3];
  float SS = rss[0] + rss[1] + rss[2] + rss[3];
  float mean = S * (1.f / 1024.f);
  float var = SS * (1.f / 1024.f) - mean * mean;
  float inv = rsqrtf(var + 1e-5f);
#pragma unroll
  for (int i = 0; i < 4; ++i) {
    int c = tid + i * 256;
    xr[c] = (v[i] - mean) * inv * g[c] + bb[c];
  }
}

// ---------------- fused: LN -> LN -> gate mix ----------------
__global__ __launch_bounds__(256) void ln2mix_kernel(const float* __restrict__ X,
                                                     const float* __restrict__ g1, const float* __restrict__ b1,
                                                     const float* __restrict__ g2, const float* __restrict__ b2,
                                                     const float* __restrict__ gpre, const float* __restrict__ bgate,
                                                     const float* __restrict__ fo, float* __restrict__ outp) {
  int row = blockIdx.x, tid = threadIdx.x;
  const float* xr = X + (size_t)row * D_;
  __shared__ float rs[4], rss[4];
  float v[4], s = 0.f, ss = 0.f;
#pragma unroll
  for (int i = 0; i < 4; ++i) { v[i] = xr[tid + i * 256]; s += v[i]; ss += v[i] * v[i]; }
#pragma unroll
  for (int off = 32; off; off >>= 1) { s += __shfl_xor(s, off); ss += __shfl_xor(ss, off); }
  if ((tid & 63) == 0) { rs[tid >> 6] = s; rss[tid >> 6] = ss; }
  __syncthreads();
  float S = rs[0] + rs[1] + rs[2] + rs[3];
  float SS = rss[0] + rss[1] + rss[2] + rss[3];
  float mean = S * (1.f / 1024.f);
  float var = SS * (1.f / 1024.f) - mean * mean;
  float inv = rsqrtf(var + 1e-5f);
  s = 0.f; ss = 0.f;
#pragma unroll
  for (int i = 0; i < 4; ++i) {
    int c = tid + i * 256;
    v[i] = (v[i] - mean) * inv * g1[c] + b1[c];
    s += v[i]; ss += v[i] * v[i];
  }
#pragma unroll
  for (int off = 32; off; off >>= 1) { s += __shfl_xor(s, off); ss += __shfl_xor(ss, off); }
  __syncthreads();
  if ((tid & 63) == 0) { rs[tid >> 6] = s; rss[tid >> 6] = ss; }
  __syncthreads();
  S = rs[0] + rs[1] + rs[2] + rs[3];
  SS = rss[0] + rss[1] + rss[2] + rss[3];
  mean = S * (1.f / 1024.f);
  var = SS * (1.f / 1024.f) - mean * mean;
  inv = rsqrtf(var + 1e-5f);
#pragma unroll
  for (int i = 0; i < 4; ++i) {
    int c = tid + i * 256;
    size_t idx = (size_t)row * D_ + c;
    float w = (v[i] - mean) * inv * g2[c] + b2[c];
    float gg = 1.f / (1.f + __expf(-(gpre[idx] + bgate[c])));
    outp[idx] = gg * fo[idx] + (1.f - gg) * w;
  }
}

// ---------------- fused conv (q) / conv+L2norm (k) ----------------
__global__ __launch_bounds__(256) void convnorm_kernel(const float* __restrict__ qin, const float* __restrict__ kin,
                                                       const float* __restrict__ qw, const float* __restrict__ qb,
                                                       const float* __restrict__ kw, const float* __restrict__ kb,
                                                       float* __restrict__ qout, float* __restrict__ kout) {
  int path = blockIdx.y;
  int row = blockIdx.x * 4 + (threadIdx.x >> 6);
  int lane = threadIdx.x & 63;
  int bl = row >> 4, h = row & 15;
  int t = bl & (L_ - 1);
  int d = h * 64 + lane;
  size_t idx = (size_t)bl * D_ + d;
  const float* xin = path ? kin : qin;
  const float* w = path ? kw : qw;
  const float* bias = path ? kb : qb;
  float acc = bias[d];
#pragma unroll
  for (int j = 0; j < 4; ++j) {
    int tt = t - 3 + j;
    if (tt >= 0) acc += w[d * 4 + j] * xin[idx + (size_t)(j - 3) * D_];
  }
  if (path) {
    float n2 = acc * acc;
#pragma unroll
    for (int off = 32; off; off >>= 1) n2 += __shfl_xor(n2, off);
    acc = acc / fmaxf(sqrtf(n2), 1e-12f);
    kout[idx] = acc;
  } else {
    qout[idx] = acc;
  }
}

// ---------------- beta = sigmoid(x @ Wbeta + bbeta) ----------------
__global__ __launch_bounds__(256) void beta_kernel(const float* __restrict__ xf, const float* __restrict__ Wb,
                                                   const float* __restrict__ bb, float* __restrict__ beta) {
  int row = blockIdx.x, tid = threadIdx.x;
  int h = tid & 15, seg = tid >> 4;
  const float* xr = xf + (size_t)row * D_ + seg * 64;
  const float* wp = Wb + (seg * 64) * H_ + h;
  float p = 0.f;
  for (int k = 0; k < 64; ++k) p += xr[k] * wp[k * H_];
  __shared__ float red[16][17];
  red[seg][h] = p;
  __syncthreads();
  if (tid < 16) {
    float s = bb[tid];
#pragma unroll
    for (int s2 = 0; s2 < 16; ++s2) s += red[s2][tid];
    beta[(size_t)row * H_ + tid] = 1.f / (1.f + __expf(-s));
  }
}

// ================= chunked delta scan =================
__global__ __launch_bounds__(256) void prep_kernel(const float* __restrict__ dq, const float* __restrict__ dk,
                                                   const float* __restrict__ beta,
                                                   float* __restrict__ Minv_g, float* __restrict__ Bq_g) {
  __shared__ __align__(16) float Kl[32 * 68];
  __shared__ __align__(16) float Ql[32 * 68];
  __shared__ __align__(16) float Ml[32 * 36];
  __shared__ __align__(16) float Xl[32 * 36];
  __shared__ __align__(16) float bl[32];
  int c = blockIdx.x, bh = blockIdx.y;
  int b = bh >> 4, h = bh & 15;
  int t0 = c * 32;
  int tid = threadIdx.x;
#pragma unroll
  for (int rep = 0; rep < 2; ++rep) {
    int id = tid * 2 + rep;
    int r = id >> 4, j4 = id & 15;
    size_t gi = (size_t)(b * L_ + t0 + r) * 1024 + h * 64 + j4 * 4;
    *(float4*)&Kl[r * 68 + j4 * 4] = *(const float4*)&dk[gi];
    *(float4*)&Ql[r * 68 + j4 * 4] = *(const float4*)&dq[gi];
  }
  if (tid < 32) bl[tid] = beta[(size_t)(b * L_ + t0 + tid) * 16 + h];
  __syncthreads();
  int t = tid >> 3, s0 = (tid & 7) * 4;
  float accA[4] = {0.f, 0.f, 0.f, 0.f}, accB[4] = {0.f, 0.f, 0.f, 0.f};
#pragma unroll
  for (int k4 = 0; k4 < 16; ++k4) {
    float4 kt = *(float4*)&Kl[t * 68 + k4 * 4];
    float4 qt = *(float4*)&Ql[t * 68 + k4 * 4];
#pragma unroll
    for (int j = 0; j < 4; ++j) {
      float4 ks = *(float4*)&Kl[(s0 + j) * 68 + k4 * 4];
      accA[j] += dot4(kt, ks);
      accB[j] += dot4(qt, ks);
    }
  }
  float4 bq;
  float* bqp = (float*)&bq;
#pragma unroll
  for (int j = 0; j < 4; ++j) {
    int s = s0 + j;
    Ml[t * 36 + s] = (s < t) ? bl[t] * accA[j] : ((s == t) ? 1.f : 0.f);
    bqp[j] = (s < t) ? accB[j] : 0.f;
  }
  size_t obase = ((size_t)(bh * 64 + c) * 32 + t) * 32 + s0;
  *(float4*)&Bq_g[obase] = bq;
  __syncthreads();
  if (tid < 32) {
    int col = tid;
    float xr[32];
#pragma unroll
    for (int tt = 0; tt < 32; ++tt) {
      float x = (tt == col) ? 1.f : 0.f;
#pragma unroll
      for (int s = 0; s < tt; ++s) x -= Ml[tt * 36 + s] * xr[s];
      xr[tt] = x;
      Xl[tt * 36 + col] = x;
    }
  }
  __syncthreads();
  float4 mv = make_float4(Xl[t * 36 + s0], Xl[t * 36 + s0 + 1], Xl[t * 36 + s0 + 2], Xl[t * 36 + s0 + 3]);
  *(float4*)&Minv_g[obase] = mv;
}

// double-buffered; XCD-locality swizzle (bh = blockIdx & 31).
__global__ __launch_bounds__(256) void delta_kernel(const float* __restrict__ dq, const float* __restrict__ dk,
                                                    const float* __restrict__ dv, const float* __restrict__ beta,
                                                    const float* __restrict__ Minv_g, const float* __restrict__ Bq_g,
                                                    float* __restrict__ ys, float* __restrict__ outS,
                                                    float* __restrict__ outZ) {
  __shared__ __align__(16) float Kl[2][32 * 68];
  __shared__ __align__(16) float Ql[2][32 * 68];
  __shared__ __align__(16) float Vl[2][32 * 9];
  __shared__ __align__(16) float Mil[2][32 * 36];
  __shared__ __align__(16) float Bql[2][32 * 36];
  __shared__ __align__(16) float bl[2][32];
  __shared__ __align__(16) float S0l[8 * 68];
  __shared__ __align__(16) float Y0l[32 * 9];
  __shared__ __align__(16) float RtmpTl[8 * 36];
  __shared__ __align__(16) float RTl[8 * 36];
  __shared__ __align__(16) float z0l[68];
  __shared__ __align__(16) float qzl[32];
  __shared__ __align__(16) float denl[32];
  int bh = blockIdx.x & 31, grp = blockIdx.x >> 5;
  int b = bh >> 4, h = bh & 15;
  int i0 = grp * 8;
  int tid = threadIdx.x;
  int r = tid >> 3, j8 = (tid & 7) * 8, s4 = tid & 7;
  size_t kqbase = (size_t)(b * L_) * 1024 + h * 64;

  for (int e = tid; e < 8 * 68; e += 256) S0l[e] = 0.f;
  if (tid < 68) z0l[tid] = 0.f;

  float4 kA, kB, qA, qB, mr, br;
  float vr, blr = 0.f;
  {
    const float* kp = dk + kqbase + (size_t)r * 1024 + j8;
    kA = ((const float4*)kp)[0]; kB = ((const float4*)kp)[1];
    const float* qp = dq + kqbase + (size_t)r * 1024 + j8;
    qA = ((const float4*)qp)[0]; qB = ((const float4*)qp)[1];
    size_t gb = ((size_t)(bh * 64) * 32 + r) * 32 + s4 * 4;
    mr = *(const float4*)&Minv_g[gb];
    br = *(const float4*)&Bq_g[gb];
    vr = dv[(size_t)(b * L_ + r) * 1024 + h * 64 + i0 + s4];
    if (tid < 32) blr = beta[(size_t)(b * L_ + tid) * 16 + h];
  }
  *(float4*)&Kl[0][r * 68 + j8] = kA; *(float4*)&Kl[0][r * 68 + j8 + 4] = kB;
  *(float4*)&Ql[0][r * 68 + j8] = qA; *(float4*)&Ql[0][r * 68 + j8 + 4] = qB;
  *(float4*)&Mil[0][r * 36 + s4 * 4] = mr;
  *(float4*)&Bql[0][r * 36 + s4 * 4] = br;
  Vl[0][r * 9 + s4] = vr;
  if (tid < 32) bl[0][tid] = blr;
  __syncthreads();

  for (int c = 0; c < 64; ++c) {
    int cur = c & 1, nxt = cur ^ 1;
    int cn = (c + 1 < 64) ? c + 1 : 63;
    int t0n = cn * 32;
    {
      const float* kp = dk + kqbase + (size_t)(t0n + r) * 1024 + j8;
      kA = ((const float4*)kp)[0]; kB = ((const float4*)kp)[1];
      const float* qp = dq + kqbase + (size_t)(t0n + r) * 1024 + j8;
      qA = ((const float4*)qp)[0]; qB = ((const float4*)qp)[1];
      size_t gb = ((size_t)(bh * 64 + cn) * 32 + r) * 32 + s4 * 4;
      mr = *(const float4*)&Minv_g[gb];
      br = *(const float4*)&Bq_g[gb];
      vr = dv[(size_t)(b * L_ + t0n + r) * 1024 + h * 64 + i0 + s4];
      if (tid < 32) blr = beta[(size_t)(b * L_ + t0n + tid) * 16 + h];
    }
    int t0 = c * 32;
    // ---- P1 ----
    {
      int rr = tid >> 3;
      int iq = (tid >> 1) & 3;
      int jh = tid & 1;
      float aK0 = 0.f, aK1 = 0.f, aY0 = 0.f, aY1 = 0.f;
#pragma unroll
      for (int jj = 0; jj < 8; ++jj) {
        int j4 = jh * 8 + jj;
        float4 k = *(float4*)&Kl[cur][rr * 68 + j4 * 4];
        float4 q = *(float4*)&Ql[cur][rr * 68 + j4 * 4];
        float4 sA = *(float4*)&S0l[iq * 68 + j4 * 4];
        float4 sB = *(float4*)&S0l[(iq + 4) * 68 + j4 * 4];
        aK0 += dot4(k, sA); aK1 += dot4(k, sB);
        aY0 += dot4(q, sA); aY1 += dot4(q, sB);
      }
      aK0 += __shfl_xor(aK0, 1); aK1 += __shfl_xor(aK1, 1);
      aY0 += __shfl_xor(aY0, 1); aY1 += __shfl_xor(aY1, 1);
      if (jh == 0) {
        float be = bl[cur][rr];
        RtmpTl[iq * 36 + rr] = be * (Vl[cur][rr * 9 + iq] - aK0);
        RtmpTl[(iq + 4) * 36 + rr] = be * (Vl[cur][rr * 9 + iq + 4] - aK1);
        Y0l[rr * 9 + iq] = aY0;
        Y0l[rr * 9 + iq + 4] = aY1;
      }
      if (tid < 32) {
        float a = 0.f;
#pragma unroll
        for (int j4 = 0; j4 < 16; ++j4) {
          float4 q = *(float4*)&Ql[cur][tid * 68 + j4 * 4];
          float4 z = *(float4*)&z0l[j4 * 4];
          a += dot4(q, z);
        }
        qzl[tid] = a;
      }
    }
    __syncthreads();
    // ---- P2 ----
    {
      int t = tid >> 3, i = tid & 7;
      float acc = 0.f;
#pragma unroll
      for (int s4i = 0; s4i < 8; ++s4i) {
        float4 m = *(float4*)&Mil[cur][t * 36 + s4i * 4];
        float4 rt = *(float4*)&RtmpTl[i * 36 + s4i * 4];
        acc += dot4(m, rt);
      }
      RTl[i * 36 + t] = acc;
      if (tid < 32) {
        float a = qzl[tid];
#pragma unroll
        for (int s4i = 0; s4i < 8; ++s4i) {
          float4 bq = *(float4*)&Bql[cur][tid * 36 + s4i * 4];
          float4 be = *(float4*)&bl[cur][s4i * 4];
          a += dot4(bq, be);
        }
        denl[tid] = a + 1e-6f;
      }
    }
    __syncthreads();
    // ---- P3a ----
    {
      int t = tid >> 3, i = tid & 7;
      float acc = 0.f;
#pragma unroll
      for (int s4i = 0; s4i < 8; ++s4i) {
        float4 bq = *(float4*)&Bql[cur][t * 36 + s4i * 4];
        float4 rt = *(float4*)&RTl[i * 36 + s4i * 4];
        acc += dot4(bq, rt);
      }
      float y = (Y0l[t * 9 + i] + acc) / denl[t];
      ys[(size_t)(b * L_ + t0 + t) * 1024 + h * 64 + i0 + i] = y;
    }
    // ---- P3b ----
    {
      int i = tid >> 5;
      int j2 = (tid & 31) * 2;
      float a0 = S0l[i * 68 + j2];
      float a1 = S0l[i * 68 + j2 + 1];
#pragma unroll
      for (int s4i = 0; s4i < 8; ++s4i) {
        float4 rt = *(float4*)&RTl[i * 36 + s4i * 4];
        float2 k0 = *(float2*)&Kl[cur][(s4i * 4 + 0) * 68 + j2];
        float2 k1 = *(float2*)&Kl[cur][(s4i * 4 + 1) * 68 + j2];
        float2 k2 = *(float2*)&Kl[cur][(s4i * 4 + 2) * 68 + j2];
        float2 k3 = *(float2*)&Kl[cur][(s4i * 4 + 3) * 68 + j2];
        a0 += rt.x * k0.x + rt.y * k1.x + rt.z * k2.x + rt.w * k3.x;
        a1 += rt.x * k0.y + rt.y * k1.y + rt.z * k2.y + rt.w * k3.y;
      }
      S0l[i * 68 + j2] = a0;
      S0l[i * 68 + j2 + 1] = a1;
    }
    if (tid < 64) {
      float a = z0l[tid];
#pragma unroll
      for (int s = 0; s < 32; ++s) a += bl[cur][s] * Kl[cur][s * 68 + tid];
      z0l[tid] = a;
    }
    *(float4*)&Kl[nxt][r * 68 + j8] = kA; *(float4*)&Kl[nxt][r * 68 + j8 + 4] = kB;
    *(float4*)&Ql[nxt][r * 68 + j8] = qA; *(float4*)&Ql[nxt][r * 68 + j8 + 4] = qB;
    *(float4*)&Mil[nxt][r * 36 + s4 * 4] = mr;
    *(float4*)&Bql[nxt][r * 36 + s4 * 4] = br;
    Vl[nxt][r * 9 + s4] = vr;
    if (tid < 32) bl[nxt][tid] = blr;
    __syncthreads();
  }
  {
    int i = tid >> 5, j2 = (tid & 31) * 2;
    *(float2*)&outS[((size_t)(bh * 64) + i0 + i) * 64 + j2] = *(float2*)&S0l[i * 68 + j2];
  }
  if (grp == 0 && tid < 64) outZ[bh * 64 + tid] = z0l[tid];
}

extern "C" void kernel_launch(void* const* d_in, const int* in_sizes, int n_in,
                              void* d_out, int out_size, void* d_ws, size_t ws_size,
                              hipStream_t stream) {
  const float* x     = (const float*)d_in[0];
  const float* Wqkv  = (const float*)d_in[1];
  const float* Wout  = (const float*)d_in[2];
  const float* Wgate = (const float*)d_in[3];
  const float* bgate = (const float*)d_in[4];
  const float* fn_g  = (const float*)d_in[5];
  const float* fn_b  = (const float*)d_in[6];
  const float* dn_g  = (const float*)d_in[7];
  const float* dn_b  = (const float*)d_in[8];
  const float* dWq   = (const float*)d_in[9];
  const float* dWk   = (const float*)d_in[10];
  const float* dWv   = (const float*)d_in[11];
  const float* dWo   = (const float*)d_in[12];
  const float* Wbeta = (const float*)d_in[13];
  const float* bbeta = (const float*)d_in[14];
  const float* cq_w  = (const float*)d_in[15];
  const float* cq_b  = (const float*)d_in[16];
  const float* ck_w  = (const float*)d_in[17];
  const float* ck_b  = (const float*)d_in[18];
  const float* ln_g  = (const float*)d_in[19];
  const float* ln_b  = (const float*)d_in[20];

  float* ws = (float*)d_ws;
  short* qkvh   = (short*)ws;      // [0,6.3M floats) as bf16; dead after attn
  float* dv     = ws;              // [0,4M)  after attn
  float* dqc    = ws + 4194304;    // [4M,8M)   after attn
  float* dkc    = ws + 8388608;    // [8M,12M)  after attn
  float* attnO  = ws + 12582912;   // [12M,16M)
  short* wtg    = (short*)(ws + 12582912); // [12M,12.5M) after attnO dead
  short* Wvt    = (short*)(ws + 14680064); // [14M,14.5M) before Bq written
  float* Minv_g = ws + 12582912;   // [12M,14M) prep output
  float* Bq_g   = ws + 14680064;   // [14M,16M)
  float* do1    = ws + 12582912;
  float* fo     = ws + 16777216;   // [16M,20M)
  float* dqp    = ws + 20971520;   // [20M,24M)
  float* gpre   = ws + 20971520;
  float* dkp    = ws + 25165824;   // [24M,28M)
  float* ysb    = ws + 25165824;
  float* betab  = ws + 29360128;   // [28M,+64K floats)

  short* Wqkvt = (short*)(ws + 20971520); // [20M,21.5M); dead before dqp write? NO -> see order
  short* Woutt = (short*)(ws + 29426688); // [28M+64K, +0.5M)
  short* Wot   = (short*)(ws + 4194304);  // dqc dead after delta

  float* out  = (float*)d_out;
  float* outS = out + 4194304;
  float* outZ = out + 4325376;

  // ---- flash branch ----
  tcast<<<dim3(48, 16), 256, 0, stream>>>(Wqkv, Wqkvt, 3072, 1024);          // Wqkvt@[20M); dqp written later
  gemm_bt_h<<<dim3(24, 32), 256, 0, stream>>>(x, Wqkvt, qkvh, 3072, 1024);   // qkv bf16 @[0,6.3M)
  attn_mfma<<<dim3(32, H_, B_), 256, 0, stream>>>(qkvh, attnO);
  tcast<<<dim3(16, 16), 256, 0, stream>>>(Wout, Woutt, 1024, 1024);          // Woutt@[28M+64K)
  gemm_bt<64><<<dim3(16, 32), 256, 0, stream>>>(attnO, Woutt, fo, 1024, 1024);
  ln_kernel<<<4096, 256, 0, stream>>>(fo, fn_g, fn_b);
  // ---- delta branch ----
  gemm_ff2<<<dim3(16, 64), 256, 0, stream>>>(x, dWq, dWk, dqp, dkp, 1024, 1024); // kills Wqkvt (dead)
  convnorm_kernel<<<dim3(16384, 2), 256, 0, stream>>>(dqp, dkp, cq_w, cq_b, ck_w, ck_b, dqc, dkc); // kills qkvh
  beta_kernel<<<4096, 256, 0, stream>>>(x, Wbeta, bbeta, betab);
  tcast2<<<dim3(16, 16, 2), 256, 0, stream>>>(dWv, Wgate, Wvt, wtg);         // attnO dead; Wvt@14M, wtg@12M
  gemm_bt2<<<dim3(16, 32, 2), 256, 0, stream>>>(x, Wvt, wtg, dv, gpre);      // gpre kills dqp (dead)
  prep_kernel<<<dim3(64, 32), 256, 0, stream>>>(dqc, dkc, betab, Minv_g, Bq_g); // kills wtg/Wvt
  delta_kernel<<<256, 256, 0, stream>>>(dqc, dkc, dv, betab, Minv_g, Bq_g, ysb, outS, outZ);
  tcast<<<dim3(16, 16), 256, 0, stream>>>(dWo, Wot, 1024, 1024);             // dqc dead
  gemm_bt<64><<<dim3(16, 32), 256, 0, stream>>>(ysb, Wot, do1, 1024, 1024);  // kills Minv/Bq
  ln2mix_kernel<<<4096, 256, 0, stream>>>(do1, ln_g, ln_b, dn_g, dn_b, gpre, bgate, fo, out);
}